// Round 9
// baseline (968.531 us; speedup 1.0000x reference)
//
#include <hip/hip_runtime.h>

// ---------------------------------------------------------------------------
// DGI forward, round 9 (round-8 crash de-risk: proven BK=32 GEMM restored):
//  - U table eliminated: neg term = ratio[e] * T[qcsr[e]] with
//    ratio[e]=dinv[src]/dinv[perm[src]] built in k_fill
//    -> GEMM1 epilogue is pure coalesced scaled T writes (no scatter)
//  - agg kernels: 2 edges per gather instruction (half-wave per edge,
//    16B/lane over 512B rows), __shfl_xor(32) combine
//  - GEMM: BK=32, 3-plane LDS staging (w0/w3 A, w1 Bhi, w2 Blo) - proven r5/r7
// ---------------------------------------------------------------------------

typedef __attribute__((ext_vector_type(8))) short bh8;     // 8 bf16 (4 VGPR)
typedef __attribute__((ext_vector_type(4))) float f4;      // MFMA acc / NT f32x4
typedef __attribute__((ext_vector_type(4))) unsigned short u16x4;
typedef __attribute__((ext_vector_type(8))) unsigned short u16x8;

#define AS1 __attribute__((address_space(1)))
#define AS3 __attribute__((address_space(3)))

__device__ __forceinline__ unsigned short f2b(float f) {   // f32 -> bf16 RTNE
    unsigned int u = __float_as_uint(f);
    unsigned int r = (u + 0x7FFFu + ((u >> 16) & 1u)) >> 16;
    return (unsigned short)r;
}
__device__ __forceinline__ float b2f(unsigned short h) {
    return __uint_as_float(((unsigned int)h) << 16);
}

// ----------------------------- CSR build -----------------------------------
__global__ void k_degree(const int* __restrict__ dst, int* __restrict__ deg, int E) {
    int e = blockIdx.x * blockDim.x + threadIdx.x;
    if (e < E) atomicAdd(&deg[dst[e]], 1);
}

__global__ void k_dinv(const int* __restrict__ deg, float* __restrict__ dinv,
                       int* __restrict__ rowptr, int N, int E) {
    int n = blockIdx.x * blockDim.x + threadIdx.x;
    if (n < N) dinv[n] = 1.0f / sqrtf(1.0f + (float)deg[n]);
    if (n == 0) rowptr[N] = E;
}

__global__ void k_scanA(const int* __restrict__ in, int* __restrict__ out,
                        int* __restrict__ bsum, int n) {
    __shared__ int sh[256];
    int t = threadIdx.x;
    int base = blockIdx.x * 1024 + t * 4;
    int v[4];
#pragma unroll
    for (int j = 0; j < 4; ++j) v[j] = (base + j < n) ? in[base + j] : 0;
    int s = v[0] + v[1] + v[2] + v[3];
    sh[t] = s;
    __syncthreads();
    for (int off = 1; off < 256; off <<= 1) {
        int u = (t >= off) ? sh[t - off] : 0;
        __syncthreads();
        sh[t] += u;
        __syncthreads();
    }
    int excl = sh[t] - s;
    if (t == 255) bsum[blockIdx.x] = sh[255];
    int run = excl;
#pragma unroll
    for (int j = 0; j < 4; ++j) {
        if (base + j < n) out[base + j] = run;
        run += v[j];
    }
}

__global__ void k_scanB(const int* __restrict__ bsum, int* __restrict__ boff, int nb) {
    __shared__ int sh[128];
    int t = threadIdx.x;
    int v = (t < nb) ? bsum[t] : 0;
    sh[t] = v;
    __syncthreads();
    for (int off = 1; off < 128; off <<= 1) {
        int u = (t >= off) ? sh[t - off] : 0;
        __syncthreads();
        sh[t] += u;
        __syncthreads();
    }
    boff[t] = sh[t] - v;
}

__global__ void k_scanC(int* __restrict__ out, const int* __restrict__ boff, int n) {
    int t = threadIdx.x;
    int base = blockIdx.x * 1024 + t * 4;
    int add = boff[blockIdx.x];
#pragma unroll
    for (int j = 0; j < 4; ++j)
        if (base + j < n) out[base + j] += add;
}

// fill csr (src), qcsr (perm[src]) and ratio (dinv[src]/dinv[perm[src]])
__global__ void k_fill(const int* __restrict__ src, const int* __restrict__ dst,
                       const int* __restrict__ perm, const float* __restrict__ dinv,
                       const int* __restrict__ rowptr, int* __restrict__ cursor,
                       int* __restrict__ csr, int* __restrict__ qcsr,
                       float* __restrict__ ratio, int E) {
    int e = blockIdx.x * blockDim.x + threadIdx.x;
    if (e >= E) return;
    int d = dst[e];
    int s = src[e];
    int q = perm[s];
    int p = rowptr[d] + atomicAdd(&cursor[d], 1);
    csr[p] = s;
    qcsr[p] = q;
    ratio[p] = dinv[s] / dinv[q];
}

// ------------------------- f32 -> bf16 (hi only) ----------------------------
__global__ void k_split(const float* __restrict__ in, unsigned short* __restrict__ hi,
                        long n4) {
    long i = (long)blockIdx.x * blockDim.x + threadIdx.x;
    if (i >= n4) return;
    float4 v = ((const float4*)in)[i];
    float f[4] = {v.x, v.y, v.z, v.w};
    u16x4 h;
#pragma unroll
    for (int j = 0; j < 4; ++j) h[j] = f2b(f[j]);
    ((u16x4*)hi)[i] = h;
}

// W [K][Nc] f32 -> Wt_hi/lo [Nc][K] bf16 (transpose + split, both planes)
__global__ void k_wsplitT(const float* __restrict__ W, unsigned short* __restrict__ thi,
                          unsigned short* __restrict__ tlo, int K, int Nc) {
    int t = blockIdx.x * blockDim.x + threadIdx.x;
    if (t >= K * Nc) return;
    int k = t / Nc, n = t % Nc;
    float f = W[t];
    unsigned short hb = f2b(f);
    thi[n * K + k] = hb;
    tlo[n * K + k] = f2b(f - b2f(hb));
}

// ------------- 2-pass split-bf16 MFMA GEMM (C = A@B), BK=32 -----------------
// A [M][K] bf16 (blockIdx.z picks set 0/1), B [NcB][K] hi+lo pre-transposed.
// C[r*ldC + blockIdx.z*colz + bcol + c] = f2b(dinv[r] * acc)  (bf16 out).
__global__ __launch_bounds__(256, 2) void k_gemm_mfma(
        const unsigned short* __restrict__ Ahi0, const unsigned short* __restrict__ Ahi1,
        const unsigned short* __restrict__ Bhi, const unsigned short* __restrict__ Blo,
        unsigned short* __restrict__ C, const float* __restrict__ dinv,
        int M, int K, int NcB, int ldC, int colz) {
    __shared__ short lds[3][128 * 32];          // planes: A, Bhi, Blo (24 KB)
    const int tid  = threadIdx.x;
    const int lane = tid & 63;
    const int w    = tid >> 6;                  // wave 0..3
    const int wr   = w >> 1, wc = w & 1;
    const int row0 = blockIdx.y * 128;
    const int bcol = blockIdx.x * 128;
    const unsigned short* Ahi = blockIdx.z ? Ahi1 : Ahi0;

    // staging: w0 -> A slabs 0-3, w3 -> A slabs 4-7, w1 -> Bhi, w2 -> Blo
    const unsigned short* sp = (w == 1) ? Bhi : (w == 2) ? Blo : Ahi;
    const int  plane = (w == 1) ? 1 : (w == 2) ? 2 : 0;
    const int  slab0 = (w == 3) ? 4 : 0;
    const int  nslab = (w == 0 || w == 3) ? 4 : 8;
    const int  base0 = (w == 1 || w == 2) ? bcol : row0;
    const int  lim   = (w == 1 || w == 2) ? (NcB - 1) : (M - 1);
    const int  rsub  = lane >> 2;               // 0..15 row within slab
    const int  clin  = lane & 3;                // 16B chunk within 64B row

    f4 acc[4][4] = {};
    const int fr = lane & 15;
    const int fc = (lane >> 4) * 8;

    for (int k0 = 0; k0 < K; k0 += 32) {
        __syncthreads();
        for (int s = 0; s < nslab; ++s) {
            int slab = slab0 + s;
            int r = slab * 16 + rsub;
            int g = base0 + r;
            if (g > lim) g = lim;
            const unsigned short* srcp = sp + (size_t)g * K + k0 + clin * 8;
            __builtin_amdgcn_global_load_lds((const AS1 void*)srcp,
                                             (AS3 void*)&lds[plane][slab * 512], 16, 0, 0);
        }
        __syncthreads();

        bh8 ah[4], bhh[4], bll[4];
#pragma unroll
        for (int m = 0; m < 4; ++m)
            ah[m] = *(const bh8*)&lds[0][(wr * 64 + m * 16 + fr) * 32 + fc];
#pragma unroll
        for (int n = 0; n < 4; ++n) {
            int off = (wc * 64 + n * 16 + fr) * 32 + fc;
            bhh[n] = *(const bh8*)&lds[1][off];
            bll[n] = *(const bh8*)&lds[2][off];
        }
#pragma unroll
        for (int m = 0; m < 4; ++m)
#pragma unroll
            for (int n = 0; n < 4; ++n)
                acc[m][n] = __builtin_amdgcn_mfma_f32_16x16x32_bf16(ah[m], bhh[n], acc[m][n], 0, 0, 0);
#pragma unroll
        for (int m = 0; m < 4; ++m)
#pragma unroll
            for (int n = 0; n < 4; ++n)
                acc[m][n] = __builtin_amdgcn_mfma_f32_16x16x32_bf16(ah[m], bll[n], acc[m][n], 0, 0, 0);
    }

    // C/D layout: col=lane&15, row=(lane>>4)*4+reg
    const int cr = (lane >> 4) * 4;
    const int cc = lane & 15;
    const int cbase = blockIdx.z * colz + bcol;
#pragma unroll
    for (int m = 0; m < 4; ++m) {
        int r0 = row0 + wr * 64 + m * 16 + cr;
#pragma unroll
        for (int j = 0; j < 4; ++j) {
            int r = r0 + j;
            if (r >= M) continue;
            float sr = dinv[r];
#pragma unroll
            for (int n = 0; n < 4; ++n) {
                int c = cbase + wc * 64 + n * 16 + cc;
                C[(size_t)r * ldC + c] = f2b(sr * acc[m][n][j]);
            }
        }
    }
}

// ---- layer-1 aggregate over T [N][256] bf16 (pre-scaled by dinv) -----------
// pos[n] = relu(dn*(sum T[s] + T[n]) + b)
// neg[n] = relu(dn*(sum ratio[e]*T[qcsr[e]] + (dn/dinv[pn])*T[pn]) + b)
// 2 edges per gather instruction: half-wave h=lane>>5 owns edge e+h; 16B/lane.
__global__ __launch_bounds__(256) void k_aggT(
        const unsigned short* __restrict__ T, const int* __restrict__ rowptr,
        const int* __restrict__ csr, const int* __restrict__ qcsr,
        const float* __restrict__ ratio, const int* __restrict__ perm,
        const float* __restrict__ dinv, const float* __restrict__ bias,
        unsigned short* __restrict__ Bp, unsigned short* __restrict__ Bn, int n) {
    int wid = (blockIdx.x * blockDim.x + threadIdx.x) >> 6;
    int lane = threadIdx.x & 63;
    if (wid >= n) return;
    const int h = lane >> 5, l5 = lane & 31;
    const int off = l5 * 8;                     // 8 bf16 = 16B per lane
    int beg = rowptr[wid], end = rowptr[wid + 1];
    float ap[8] = {0.f,0.f,0.f,0.f,0.f,0.f,0.f,0.f};
    float an[8] = {0.f,0.f,0.f,0.f,0.f,0.f,0.f,0.f};
    int e = beg;
    for (; e + 3 < end; e += 4) {               // 2 pair-steps (4 edges)
        int sA = csr[e + h],     qA = qcsr[e + h];     float rA = ratio[e + h];
        int sB = csr[e + 2 + h], qB = qcsr[e + 2 + h]; float rB = ratio[e + 2 + h];
        u16x8 vpA = *(const u16x8*)(T + (size_t)sA * 256 + off);
        u16x8 vnA = *(const u16x8*)(T + (size_t)qA * 256 + off);
        u16x8 vpB = *(const u16x8*)(T + (size_t)sB * 256 + off);
        u16x8 vnB = *(const u16x8*)(T + (size_t)qB * 256 + off);
#pragma unroll
        for (int j = 0; j < 8; ++j) {
            ap[j] += b2f(vpA[j]) + b2f(vpB[j]);
            an[j] += rA * b2f(vnA[j]) + rB * b2f(vnB[j]);
        }
    }
    for (; e < end; e += 2) {                   // pair tail (1-3 edges)
        int idx = e + h;
        bool act = idx < end;
        int ic = act ? idx : e;                 // safe address
        int s = csr[ic], q = qcsr[ic];
        float r = ratio[ic];
        u16x8 vp = *(const u16x8*)(T + (size_t)s * 256 + off);
        u16x8 vn = *(const u16x8*)(T + (size_t)q * 256 + off);
        if (act) {
#pragma unroll
            for (int j = 0; j < 8; ++j) {
                ap[j] += b2f(vp[j]);
                an[j] += r * b2f(vn[j]);
            }
        }
    }
    // self terms: h==0 -> pos self T[wid] (weight 1); h==1 -> neg self
    float dn = dinv[wid];
    int pn = perm[wid];
    int sidx = h ? pn : wid;
    float swt = h ? (dn / dinv[pn]) : 1.0f;
    u16x8 vs = *(const u16x8*)(T + (size_t)sidx * 256 + off);
    if (h == 0) {
#pragma unroll
        for (int j = 0; j < 8; ++j) ap[j] += b2f(vs[j]);
    } else {
#pragma unroll
        for (int j = 0; j < 8; ++j) an[j] += swt * b2f(vs[j]);
    }
    // combine half-waves
#pragma unroll
    for (int j = 0; j < 8; ++j) {
        ap[j] += __shfl_xor(ap[j], 32);
        an[j] += __shfl_xor(an[j], 32);
    }
    float4 bv0 = *(const float4*)(bias + off);
    float4 bv1 = *(const float4*)(bias + off + 4);
    float bb8[8] = {bv0.x, bv0.y, bv0.z, bv0.w, bv1.x, bv1.y, bv1.z, bv1.w};
    u16x8 o;
#pragma unroll
    for (int j = 0; j < 8; ++j) {
        float v = h ? an[j] : ap[j];
        o[j] = f2b(fmaxf(dn * v + bb8[j], 0.f));
    }
    unsigned short* dstp = (h ? Bn : Bp) + (size_t)wid * 256 + off;
    __builtin_nontemporal_store(o, (u16x8*)dstp);
}

// ---- layer-2 aggregate over pre-scaled G2 [N][256] = [pos|neg] -------------
// 2 edges per gather instruction; final H split to Hpos/Hneg (f32).
__global__ __launch_bounds__(256) void k_aggT2(
        const unsigned short* __restrict__ G2, const int* __restrict__ rowptr,
        const int* __restrict__ csr, const float* __restrict__ dinv,
        const float* __restrict__ bias, float* __restrict__ Hpos,
        float* __restrict__ Hneg, int n) {
    int wid = (blockIdx.x * blockDim.x + threadIdx.x) >> 6;
    int lane = threadIdx.x & 63;
    if (wid >= n) return;
    const int h = lane >> 5, l5 = lane & 31;
    const int off = l5 * 8;
    int beg = rowptr[wid], end = rowptr[wid + 1];
    float a[8] = {0.f,0.f,0.f,0.f,0.f,0.f,0.f,0.f};
    int e = beg;
    for (; e + 3 < end; e += 4) {
        int sA = csr[e + h], sB = csr[e + 2 + h];
        u16x8 vA = *(const u16x8*)(G2 + (size_t)sA * 256 + off);
        u16x8 vB = *(const u16x8*)(G2 + (size_t)sB * 256 + off);
#pragma unroll
        for (int j = 0; j < 8; ++j) a[j] += b2f(vA[j]) + b2f(vB[j]);
    }
    for (; e < end; e += 2) {
        int idx = e + h;
        bool act = idx < end;
        int ic = act ? idx : e;
        int s = csr[ic];
        u16x8 v = *(const u16x8*)(G2 + (size_t)s * 256 + off);
        if (act) {
#pragma unroll
            for (int j = 0; j < 8; ++j) a[j] += b2f(v[j]);
        }
    }
    if (h == 0) {                               // self term once
        u16x8 vs = *(const u16x8*)(G2 + (size_t)wid * 256 + off);
#pragma unroll
        for (int j = 0; j < 8; ++j) a[j] += b2f(vs[j]);
    }
#pragma unroll
    for (int j = 0; j < 8; ++j) a[j] += __shfl_xor(a[j], 32);

    if (h == 0) {                               // lanes 0..31 write
        float dn = dinv[wid];
        int col = (l5 < 16) ? off : (off - 128);     // within 128-dim table
        const float* bp = bias + col;
        float* dstp = ((l5 < 16) ? Hpos : Hneg) + (size_t)wid * 128 + col;
        f4 r0, r1;
#pragma unroll
        for (int j = 0; j < 4; ++j) r0[j] = dn * a[j] + bp[j];
#pragma unroll
        for (int j = 0; j < 4; ++j) r1[j] = dn * a[4 + j] + bp[4 + j];
        __builtin_nontemporal_store(r0, (f4*)dstp);
        __builtin_nontemporal_store(r1, (f4*)(dstp + 4));
    }
}

// ----------------------------- tail kernels ---------------------------------
__global__ void k_colsum(const float* __restrict__ H, float* __restrict__ colsum, int n) {
    int c = threadIdx.x & 127, half = threadIdx.x >> 7;
    float acc = 0.f;
    for (int r = blockIdx.x * 2 + half; r < n; r += gridDim.x * 2)
        acc += H[(size_t)r * 128 + c];
    __shared__ float sh[256];
    sh[threadIdx.x] = acc;
    __syncthreads();
    if (half == 0) atomicAdd(&colsum[c], sh[c] + sh[c + 128]);
}

__global__ void k_summary(const float* __restrict__ colsum, const float* __restrict__ Wb,
                          float* __restrict__ t, int n) {
    __shared__ float s_sh[128];
    int d = threadIdx.x;
    float m = colsum[d] / (float)n;
    s_sh[d] = 1.0f / (1.0f + expf(-m));
    __syncthreads();
    float acc = 0.f;
    for (int e = 0; e < 128; ++e) acc += Wb[d * 128 + e] * s_sh[e];
    t[d] = acc;
}

// merged disc over 2N nodes: wid<n -> Hpos, else Hneg
__global__ void k_disc(const float* __restrict__ Hpos, const float* __restrict__ Hneg,
                       const float* __restrict__ t, const float* __restrict__ bb,
                       float* __restrict__ out, int n) {
    int wid = (blockIdx.x * blockDim.x + threadIdx.x) >> 6;
    int lane = threadIdx.x & 63;
    if (wid >= 2 * n) return;
    const float* row = (wid < n) ? (Hpos + (size_t)wid * 128)
                                 : (Hneg + (size_t)(wid - n) * 128);
    float p = row[lane] * t[lane] + row[lane + 64] * t[lane + 64];
#pragma unroll
    for (int off = 32; off > 0; off >>= 1) p += __shfl_down(p, off);
    if (lane == 0) out[wid] = p + bb[0];
}

// ---------------------------------------------------------------------------
extern "C" void kernel_launch(void* const* d_in, const int* in_sizes, int n_in,
                              void* d_out, int out_size, void* d_ws, size_t ws_size,
                              hipStream_t stream) {
    const float* x    = (const float*)d_in[0];
    const int*   ei   = (const int*)d_in[1];
    const int*   perm = (const int*)d_in[2];
    const float* W1   = (const float*)d_in[3];
    const float* b1   = (const float*)d_in[4];
    const float* W2   = (const float*)d_in[5];
    const float* b2   = (const float*)d_in[6];
    const float* Wb   = (const float*)d_in[7];
    const float* bb   = (const float*)d_in[8];
    float* out = (float*)d_out;

    const int N   = in_sizes[2];
    const int E   = in_sizes[1] / 2;
    const int IN  = in_sizes[0] / N;   // 256
    const int HID = in_sizes[4];       // 256
    const int OUT = in_sizes[6];       // 128
    const int* src = ei;
    const int* dst = ei + E;

    char* p = (char*)d_ws;
    auto alloc = [&](size_t bytes) -> void* {
        void* r = (void*)p;
        p += (bytes + 255) & ~(size_t)255;
        return r;
    };
    int*   deg    = (int*)alloc((size_t)N * 4);
    int*   cursor = (int*)alloc((size_t)N * 4);
    float* colsum = (float*)alloc(128 * 4);
    size_t zlen   = (size_t)(p - (char*)deg);
    int*   rowptr = (int*)alloc((size_t)(N + 1) * 4);
    int*   bsum   = (int*)alloc(128 * 4);
    int*   boff   = (int*)alloc(128 * 4);
    int*   csr    = (int*)alloc((size_t)E * 4);
    int*   qcsr   = (int*)alloc((size_t)E * 4);
    float* ratio  = (float*)alloc((size_t)E * 4);
    float* dinv   = (float*)alloc((size_t)N * 4);
    float* tvec   = (float*)alloc(128 * 4);
    unsigned short* W1thi = (unsigned short*)alloc((size_t)IN * HID * 2);
    unsigned short* W1tlo = (unsigned short*)alloc((size_t)IN * HID * 2);
    unsigned short* W2thi = (unsigned short*)alloc((size_t)HID * OUT * 2);
    unsigned short* W2tlo = (unsigned short*)alloc((size_t)HID * OUT * 2);
    unsigned short* Xhi = (unsigned short*)alloc((size_t)N * IN * 2);   // 51 MB
    unsigned short* Tt  = (unsigned short*)alloc((size_t)N * HID * 2);  // 51 MB
    unsigned short* Bp  = (unsigned short*)alloc((size_t)N * HID * 2);  // 51 MB
    unsigned short* Bn  = (unsigned short*)alloc((size_t)N * HID * 2);  // 51 MB

    unsigned short* G2 = Xhi;                    // Xhi dead after GEMM1
    float* Hpos = (float*)Tt;                    // Tt dead after k_aggT
    float* Hneg = (float*)Bp;                    // Bp dead after GEMM2

    hipMemsetAsync(deg, 0, zlen, stream);

    int eb = (E + 255) / 256;
    int nb = (N + 255) / 256;
    int nscan = (N + 1023) / 1024;
    k_degree<<<eb, 256, 0, stream>>>(dst, deg, E);
    k_dinv<<<nb, 256, 0, stream>>>(deg, dinv, rowptr, N, E);
    k_scanA<<<nscan, 256, 0, stream>>>(deg, rowptr, bsum, N);
    k_scanB<<<1, 128, 0, stream>>>(bsum, boff, nscan);
    k_scanC<<<nscan, 256, 0, stream>>>(rowptr, boff, N);
    k_fill<<<eb, 256, 0, stream>>>(src, dst, perm, dinv, rowptr, cursor,
                                   csr, qcsr, ratio, E);

    long n4 = (long)N * IN / 4;
    k_split<<<(int)((n4 + 255) / 256), 256, 0, stream>>>(x, Xhi, n4);
    k_wsplitT<<<(IN * HID + 255) / 256, 256, 0, stream>>>(W1, W1thi, W1tlo, IN, HID);
    k_wsplitT<<<(HID * OUT + 255) / 256, 256, 0, stream>>>(W2, W2thi, W2tlo, HID, OUT);

    int mblk = (N + 127) / 128;
    int aggb = (N + 3) / 4;

    // layer 1: GEMM -> T table (scaled, coalesced); agg -> Bp, Bn
    k_gemm_mfma<<<dim3(HID / 128, mblk, 1), 256, 0, stream>>>(
        Xhi, Xhi, W1thi, W1tlo, Tt, dinv, N, IN, HID, HID, 0);
    k_aggT<<<aggb, 256, 0, stream>>>(Tt, rowptr, csr, qcsr, ratio, perm, dinv, b1,
                                     Bp, Bn, N);

    // layer 2: z=0 pos -> G2 cols 0..127, z=1 neg -> 128..255 (pre-scaled)
    k_gemm_mfma<<<dim3(OUT / 128, mblk, 2), 256, 0, stream>>>(
        Bp, Bn, W2thi, W2tlo, G2, dinv, N, HID, OUT, HID, OUT);
    k_aggT2<<<aggb, 256, 0, stream>>>(G2, rowptr, csr, dinv, b2, Hpos, Hneg, N);

    // summary + discriminator
    k_colsum<<<256, 256, 0, stream>>>(Hpos, colsum, N);
    k_summary<<<1, 128, 0, stream>>>(colsum, Wb, tvec, N);
    int db = (int)(((size_t)N * 2 * 64 + 255) / 256);
    k_disc<<<db, 256, 0, stream>>>(Hpos, Hneg, tvec, bb, out, N);
}

// Round 11
// 947.044 us; speedup vs baseline: 1.0227x; 1.0227x over previous
//
#include <hip/hip_runtime.h>

// ---------------------------------------------------------------------------
// DGI forward, round 11 (round-10 resubmit; GPU acquisition timed out):
//  - 1-pass bf16 MFMA GEMM (A_hi x B_hi): half the MFMAs, 2 LDS planes,
//    balanced 4-slab-per-wave staging  [risky change: +~2^-9 rel error]
//  - GEMM2 merged: one launch over M=2N rows (Bp|Bn contiguous), epilogue
//    routes rows to interleaved G2 [N][256] = [pos|neg]
//  - aggT / aggT2 / CSR+ratio pipeline unchanged (at gather roofline)
// ---------------------------------------------------------------------------

typedef __attribute__((ext_vector_type(8))) short bh8;     // 8 bf16 (4 VGPR)
typedef __attribute__((ext_vector_type(4))) float f4;      // MFMA acc / NT f32x4
typedef __attribute__((ext_vector_type(4))) unsigned short u16x4;
typedef __attribute__((ext_vector_type(8))) unsigned short u16x8;

#define AS1 __attribute__((address_space(1)))
#define AS3 __attribute__((address_space(3)))

__device__ __forceinline__ unsigned short f2b(float f) {   // f32 -> bf16 RTNE
    unsigned int u = __float_as_uint(f);
    unsigned int r = (u + 0x7FFFu + ((u >> 16) & 1u)) >> 16;
    return (unsigned short)r;
}
__device__ __forceinline__ float b2f(unsigned short h) {
    return __uint_as_float(((unsigned int)h) << 16);
}

// ----------------------------- CSR build -----------------------------------
__global__ void k_degree(const int* __restrict__ dst, int* __restrict__ deg, int E) {
    int e = blockIdx.x * blockDim.x + threadIdx.x;
    if (e < E) atomicAdd(&deg[dst[e]], 1);
}

__global__ void k_dinv(const int* __restrict__ deg, float* __restrict__ dinv,
                       int* __restrict__ rowptr, int N, int E) {
    int n = blockIdx.x * blockDim.x + threadIdx.x;
    if (n < N) dinv[n] = 1.0f / sqrtf(1.0f + (float)deg[n]);
    if (n == 0) rowptr[N] = E;
}

__global__ void k_scanA(const int* __restrict__ in, int* __restrict__ out,
                        int* __restrict__ bsum, int n) {
    __shared__ int sh[256];
    int t = threadIdx.x;
    int base = blockIdx.x * 1024 + t * 4;
    int v[4];
#pragma unroll
    for (int j = 0; j < 4; ++j) v[j] = (base + j < n) ? in[base + j] : 0;
    int s = v[0] + v[1] + v[2] + v[3];
    sh[t] = s;
    __syncthreads();
    for (int off = 1; off < 256; off <<= 1) {
        int u = (t >= off) ? sh[t - off] : 0;
        __syncthreads();
        sh[t] += u;
        __syncthreads();
    }
    int excl = sh[t] - s;
    if (t == 255) bsum[blockIdx.x] = sh[255];
    int run = excl;
#pragma unroll
    for (int j = 0; j < 4; ++j) {
        if (base + j < n) out[base + j] = run;
        run += v[j];
    }
}

__global__ void k_scanB(const int* __restrict__ bsum, int* __restrict__ boff, int nb) {
    __shared__ int sh[128];
    int t = threadIdx.x;
    int v = (t < nb) ? bsum[t] : 0;
    sh[t] = v;
    __syncthreads();
    for (int off = 1; off < 128; off <<= 1) {
        int u = (t >= off) ? sh[t - off] : 0;
        __syncthreads();
        sh[t] += u;
        __syncthreads();
    }
    boff[t] = sh[t] - v;
}

__global__ void k_scanC(int* __restrict__ out, const int* __restrict__ boff, int n) {
    int t = threadIdx.x;
    int base = blockIdx.x * 1024 + t * 4;
    int add = boff[blockIdx.x];
#pragma unroll
    for (int j = 0; j < 4; ++j)
        if (base + j < n) out[base + j] += add;
}

// fill csr (src), qcsr (perm[src]) and ratio (dinv[src]/dinv[perm[src]])
__global__ void k_fill(const int* __restrict__ src, const int* __restrict__ dst,
                       const int* __restrict__ perm, const float* __restrict__ dinv,
                       const int* __restrict__ rowptr, int* __restrict__ cursor,
                       int* __restrict__ csr, int* __restrict__ qcsr,
                       float* __restrict__ ratio, int E) {
    int e = blockIdx.x * blockDim.x + threadIdx.x;
    if (e >= E) return;
    int d = dst[e];
    int s = src[e];
    int q = perm[s];
    int p = rowptr[d] + atomicAdd(&cursor[d], 1);
    csr[p] = s;
    qcsr[p] = q;
    ratio[p] = dinv[s] / dinv[q];
}

// ------------------------- f32 -> bf16 cast ---------------------------------
__global__ void k_split(const float* __restrict__ in, unsigned short* __restrict__ hi,
                        long n4) {
    long i = (long)blockIdx.x * blockDim.x + threadIdx.x;
    if (i >= n4) return;
    float4 v = ((const float4*)in)[i];
    float f[4] = {v.x, v.y, v.z, v.w};
    u16x4 h;
#pragma unroll
    for (int j = 0; j < 4; ++j) h[j] = f2b(f[j]);
    ((u16x4*)hi)[i] = h;
}

// W [K][Nc] f32 -> Wt [Nc][K] bf16 (transpose + cast)
__global__ void k_wT(const float* __restrict__ W, unsigned short* __restrict__ thi,
                     int K, int Nc) {
    int t = blockIdx.x * blockDim.x + threadIdx.x;
    if (t >= K * Nc) return;
    int k = t / Nc, n = t % Nc;
    thi[n * K + k] = f2b(W[t]);
}

// --------------- 1-pass bf16 MFMA GEMM (C = A@B), BK=32 ---------------------
// A [M][K] bf16, B [NcB][K] bf16 pre-transposed. Output f2b(dinv * acc).
// MODE 1: C[r*ldC + bcol + c]                      (T table; M = N)
// MODE 2: M = 2*N1; row r<N1 -> C[r][c], else C[r-N1][128+c]  (G2 interleave)
template <int MODE>
__global__ __launch_bounds__(256, 2) void k_gemm_mfma(
        const unsigned short* __restrict__ A, const unsigned short* __restrict__ B,
        unsigned short* __restrict__ C, const float* __restrict__ dinv,
        int M, int K, int NcB, int ldC, int N1) {
    __shared__ short lds[2][128 * 32];          // planes: A, B (16 KB)
    const int tid  = threadIdx.x;
    const int lane = tid & 63;
    const int w    = tid >> 6;                  // wave 0..3
    const int wr   = w >> 1, wc = w & 1;
    const int row0 = blockIdx.y * 128;
    const int bcol = blockIdx.x * 128;

    // staging: w0 -> A slabs 0-3, w3 -> A slabs 4-7, w1 -> B 0-3, w2 -> B 4-7
    const bool isB  = (w == 1 || w == 2);
    const unsigned short* sp = isB ? B : A;
    const int  plane = isB ? 1 : 0;
    const int  slab0 = (w >= 2) ? 4 : 0;
    const int  base0 = isB ? bcol : row0;
    const int  lim   = isB ? (NcB - 1) : (M - 1);
    const int  rsub  = lane >> 2;               // 0..15 row within slab
    const int  clin  = lane & 3;                // 16B chunk within 64B row

    f4 acc[4][4] = {};
    const int fr = lane & 15;
    const int fc = (lane >> 4) * 8;

    for (int k0 = 0; k0 < K; k0 += 32) {
        __syncthreads();
#pragma unroll
        for (int s = 0; s < 4; ++s) {
            int slab = slab0 + s;
            int r = slab * 16 + rsub;
            int g = base0 + r;
            if (g > lim) g = lim;
            const unsigned short* srcp = sp + (size_t)g * K + k0 + clin * 8;
            __builtin_amdgcn_global_load_lds((const AS1 void*)srcp,
                                             (AS3 void*)&lds[plane][slab * 512], 16, 0, 0);
        }
        __syncthreads();

        bh8 ah[4], bh_[4];
#pragma unroll
        for (int m = 0; m < 4; ++m)
            ah[m] = *(const bh8*)&lds[0][(wr * 64 + m * 16 + fr) * 32 + fc];
#pragma unroll
        for (int n = 0; n < 4; ++n)
            bh_[n] = *(const bh8*)&lds[1][(wc * 64 + n * 16 + fr) * 32 + fc];
#pragma unroll
        for (int m = 0; m < 4; ++m)
#pragma unroll
            for (int n = 0; n < 4; ++n)
                acc[m][n] = __builtin_amdgcn_mfma_f32_16x16x32_bf16(ah[m], bh_[n], acc[m][n], 0, 0, 0);
    }

    // C/D layout: col=lane&15, row=(lane>>4)*4+reg
    const int cr = (lane >> 4) * 4;
    const int cc = lane & 15;
#pragma unroll
    for (int m = 0; m < 4; ++m) {
        int r0 = row0 + wr * 64 + m * 16 + cr;
#pragma unroll
        for (int j = 0; j < 4; ++j) {
            int r = r0 + j;
            if (r >= M) continue;
            int rr, cb;
            if constexpr (MODE == 1) { rr = r; cb = bcol; }
            else { rr = (r < N1) ? r : r - N1; cb = (r < N1) ? 0 : 128; }
            float sr = dinv[rr];
#pragma unroll
            for (int n = 0; n < 4; ++n) {
                int c = cb + wc * 64 + n * 16 + cc;
                C[(size_t)rr * ldC + c] = f2b(sr * acc[m][n][j]);
            }
        }
    }
}

// ---- layer-1 aggregate over T [N][256] bf16 (pre-scaled by dinv) -----------
// pos[n] = relu(dn*(sum T[s] + T[n]) + b)
// neg[n] = relu(dn*(sum ratio[e]*T[qcsr[e]] + (dn/dinv[pn])*T[pn]) + b)
// 2 edges per gather instruction: half-wave h=lane>>5 owns edge e+h; 16B/lane.
__global__ __launch_bounds__(256) void k_aggT(
        const unsigned short* __restrict__ T, const int* __restrict__ rowptr,
        const int* __restrict__ csr, const int* __restrict__ qcsr,
        const float* __restrict__ ratio, const int* __restrict__ perm,
        const float* __restrict__ dinv, const float* __restrict__ bias,
        unsigned short* __restrict__ Bp, unsigned short* __restrict__ Bn, int n) {
    int wid = (blockIdx.x * blockDim.x + threadIdx.x) >> 6;
    int lane = threadIdx.x & 63;
    if (wid >= n) return;
    const int h = lane >> 5, l5 = lane & 31;
    const int off = l5 * 8;                     // 8 bf16 = 16B per lane
    int beg = rowptr[wid], end = rowptr[wid + 1];
    float ap[8] = {0.f,0.f,0.f,0.f,0.f,0.f,0.f,0.f};
    float an[8] = {0.f,0.f,0.f,0.f,0.f,0.f,0.f,0.f};
    int e = beg;
    for (; e + 3 < end; e += 4) {               // 2 pair-steps (4 edges)
        int sA = csr[e + h],     qA = qcsr[e + h];     float rA = ratio[e + h];
        int sB = csr[e + 2 + h], qB = qcsr[e + 2 + h]; float rB = ratio[e + 2 + h];
        u16x8 vpA = *(const u16x8*)(T + (size_t)sA * 256 + off);
        u16x8 vnA = *(const u16x8*)(T + (size_t)qA * 256 + off);
        u16x8 vpB = *(const u16x8*)(T + (size_t)sB * 256 + off);
        u16x8 vnB = *(const u16x8*)(T + (size_t)qB * 256 + off);
#pragma unroll
        for (int j = 0; j < 8; ++j) {
            ap[j] += b2f(vpA[j]) + b2f(vpB[j]);
            an[j] += rA * b2f(vnA[j]) + rB * b2f(vnB[j]);
        }
    }
    for (; e < end; e += 2) {                   // pair tail (1-3 edges)
        int idx = e + h;
        bool act = idx < end;
        int ic = act ? idx : e;                 // safe address
        int s = csr[ic], q = qcsr[ic];
        float r = ratio[ic];
        u16x8 vp = *(const u16x8*)(T + (size_t)s * 256 + off);
        u16x8 vn = *(const u16x8*)(T + (size_t)q * 256 + off);
        if (act) {
#pragma unroll
            for (int j = 0; j < 8; ++j) {
                ap[j] += b2f(vp[j]);
                an[j] += r * b2f(vn[j]);
            }
        }
    }
    // self terms: h==0 -> pos self T[wid] (weight 1); h==1 -> neg self
    float dn = dinv[wid];
    int pn = perm[wid];
    int sidx = h ? pn : wid;
    float swt = h ? (dn / dinv[pn]) : 1.0f;
    u16x8 vs = *(const u16x8*)(T + (size_t)sidx * 256 + off);
    if (h == 0) {
#pragma unroll
        for (int j = 0; j < 8; ++j) ap[j] += b2f(vs[j]);
    } else {
#pragma unroll
        for (int j = 0; j < 8; ++j) an[j] += swt * b2f(vs[j]);
    }
    // combine half-waves
#pragma unroll
    for (int j = 0; j < 8; ++j) {
        ap[j] += __shfl_xor(ap[j], 32);
        an[j] += __shfl_xor(an[j], 32);
    }
    float4 bv0 = *(const float4*)(bias + off);
    float4 bv1 = *(const float4*)(bias + off + 4);
    float bb8[8] = {bv0.x, bv0.y, bv0.z, bv0.w, bv1.x, bv1.y, bv1.z, bv1.w};
    u16x8 o;
#pragma unroll
    for (int j = 0; j < 8; ++j) {
        float v = h ? an[j] : ap[j];
        o[j] = f2b(fmaxf(dn * v + bb8[j], 0.f));
    }
    unsigned short* dstp = (h ? Bn : Bp) + (size_t)wid * 256 + off;
    __builtin_nontemporal_store(o, (u16x8*)dstp);
}

// ---- layer-2 aggregate over pre-scaled G2 [N][256] = [pos|neg] -------------
// 2 edges per gather instruction; final H split to Hpos/Hneg (f32).
__global__ __launch_bounds__(256) void k_aggT2(
        const unsigned short* __restrict__ G2, const int* __restrict__ rowptr,
        const int* __restrict__ csr, const float* __restrict__ dinv,
        const float* __restrict__ bias, float* __restrict__ Hpos,
        float* __restrict__ Hneg, int n) {
    int wid = (blockIdx.x * blockDim.x + threadIdx.x) >> 6;
    int lane = threadIdx.x & 63;
    if (wid >= n) return;
    const int h = lane >> 5, l5 = lane & 31;
    const int off = l5 * 8;
    int beg = rowptr[wid], end = rowptr[wid + 1];
    float a[8] = {0.f,0.f,0.f,0.f,0.f,0.f,0.f,0.f};
    int e = beg;
    for (; e + 3 < end; e += 4) {
        int sA = csr[e + h], sB = csr[e + 2 + h];
        u16x8 vA = *(const u16x8*)(G2 + (size_t)sA * 256 + off);
        u16x8 vB = *(const u16x8*)(G2 + (size_t)sB * 256 + off);
#pragma unroll
        for (int j = 0; j < 8; ++j) a[j] += b2f(vA[j]) + b2f(vB[j]);
    }
    for (; e < end; e += 2) {
        int idx = e + h;
        bool act = idx < end;
        int ic = act ? idx : e;
        int s = csr[ic];
        u16x8 v = *(const u16x8*)(G2 + (size_t)s * 256 + off);
        if (act) {
#pragma unroll
            for (int j = 0; j < 8; ++j) a[j] += b2f(v[j]);
        }
    }
    if (h == 0) {                               // self term once
        u16x8 vs = *(const u16x8*)(G2 + (size_t)wid * 256 + off);
#pragma unroll
        for (int j = 0; j < 8; ++j) a[j] += b2f(vs[j]);
    }
#pragma unroll
    for (int j = 0; j < 8; ++j) a[j] += __shfl_xor(a[j], 32);

    if (h == 0) {                               // lanes 0..31 write
        float dn = dinv[wid];
        int col = (l5 < 16) ? off : (off - 128);     // within 128-dim table
        const float* bp = bias + col;
        float* dstp = ((l5 < 16) ? Hpos : Hneg) + (size_t)wid * 128 + col;
        f4 r0, r1;
#pragma unroll
        for (int j = 0; j < 4; ++j) r0[j] = dn * a[j] + bp[j];
#pragma unroll
        for (int j = 0; j < 4; ++j) r1[j] = dn * a[4 + j] + bp[4 + j];
        __builtin_nontemporal_store(r0, (f4*)dstp);
        __builtin_nontemporal_store(r1, (f4*)(dstp + 4));
    }
}

// ----------------------------- tail kernels ---------------------------------
__global__ void k_colsum(const float* __restrict__ H, float* __restrict__ colsum, int n) {
    int c = threadIdx.x & 127, half = threadIdx.x >> 7;
    float acc = 0.f;
    for (int r = blockIdx.x * 2 + half; r < n; r += gridDim.x * 2)
        acc += H[(size_t)r * 128 + c];
    __shared__ float sh[256];
    sh[threadIdx.x] = acc;
    __syncthreads();
    if (half == 0) atomicAdd(&colsum[c], sh[c] + sh[c + 128]);
}

__global__ void k_summary(const float* __restrict__ colsum, const float* __restrict__ Wb,
                          float* __restrict__ t, int n) {
    __shared__ float s_sh[128];
    int d = threadIdx.x;
    float m = colsum[d] / (float)n;
    s_sh[d] = 1.0f / (1.0f + expf(-m));
    __syncthreads();
    float acc = 0.f;
    for (int e = 0; e < 128; ++e) acc += Wb[d * 128 + e] * s_sh[e];
    t[d] = acc;
}

// merged disc over 2N nodes: wid<n -> Hpos, else Hneg
__global__ void k_disc(const float* __restrict__ Hpos, const float* __restrict__ Hneg,
                       const float* __restrict__ t, const float* __restrict__ bb,
                       float* __restrict__ out, int n) {
    int wid = (blockIdx.x * blockDim.x + threadIdx.x) >> 6;
    int lane = threadIdx.x & 63;
    if (wid >= 2 * n) return;
    const float* row = (wid < n) ? (Hpos + (size_t)wid * 128)
                                 : (Hneg + (size_t)(wid - n) * 128);
    float p = row[lane] * t[lane] + row[lane + 64] * t[lane + 64];
#pragma unroll
    for (int off = 32; off > 0; off >>= 1) p += __shfl_down(p, off);
    if (lane == 0) out[wid] = p + bb[0];
}

// ---------------------------------------------------------------------------
extern "C" void kernel_launch(void* const* d_in, const int* in_sizes, int n_in,
                              void* d_out, int out_size, void* d_ws, size_t ws_size,
                              hipStream_t stream) {
    const float* x    = (const float*)d_in[0];
    const int*   ei   = (const int*)d_in[1];
    const int*   perm = (const int*)d_in[2];
    const float* W1   = (const float*)d_in[3];
    const float* b1   = (const float*)d_in[4];
    const float* W2   = (const float*)d_in[5];
    const float* b2   = (const float*)d_in[6];
    const float* Wb   = (const float*)d_in[7];
    const float* bb   = (const float*)d_in[8];
    float* out = (float*)d_out;

    const int N   = in_sizes[2];
    const int E   = in_sizes[1] / 2;
    const int IN  = in_sizes[0] / N;   // 256
    const int HID = in_sizes[4];       // 256
    const int OUT = in_sizes[6];       // 128
    const int* src = ei;
    const int* dst = ei + E;

    char* p = (char*)d_ws;
    auto alloc = [&](size_t bytes) -> void* {
        void* r = (void*)p;
        p += (bytes + 255) & ~(size_t)255;
        return r;
    };
    int*   deg    = (int*)alloc((size_t)N * 4);
    int*   cursor = (int*)alloc((size_t)N * 4);
    float* colsum = (float*)alloc(128 * 4);
    size_t zlen   = (size_t)(p - (char*)deg);
    int*   rowptr = (int*)alloc((size_t)(N + 1) * 4);
    int*   bsum   = (int*)alloc(128 * 4);
    int*   boff   = (int*)alloc(128 * 4);
    int*   csr    = (int*)alloc((size_t)E * 4);
    int*   qcsr   = (int*)alloc((size_t)E * 4);
    float* ratio  = (float*)alloc((size_t)E * 4);
    float* dinv   = (float*)alloc((size_t)N * 4);
    float* tvec   = (float*)alloc(128 * 4);
    unsigned short* W1t = (unsigned short*)alloc((size_t)IN * HID * 2);
    unsigned short* W2t = (unsigned short*)alloc((size_t)HID * OUT * 2);
    unsigned short* Xhi = (unsigned short*)alloc((size_t)N * IN * 2);   // 51 MB
    unsigned short* Tt  = (unsigned short*)alloc((size_t)N * HID * 2);  // 51 MB
    unsigned short* Bp  = (unsigned short*)alloc((size_t)N * HID * 2);  // 51 MB (contiguous with Bn)
    unsigned short* Bn  = (unsigned short*)alloc((size_t)N * HID * 2);  // 51 MB

    unsigned short* G2 = Xhi;                    // Xhi dead after GEMM1
    float* Hpos = (float*)Tt;                    // Tt dead after k_aggT
    float* Hneg = (float*)Bp;                    // Bp dead after GEMM2

    hipMemsetAsync(deg, 0, zlen, stream);

    int eb = (E + 255) / 256;
    int nb = (N + 255) / 256;
    int nscan = (N + 1023) / 1024;
    k_degree<<<eb, 256, 0, stream>>>(dst, deg, E);
    k_dinv<<<nb, 256, 0, stream>>>(deg, dinv, rowptr, N, E);
    k_scanA<<<nscan, 256, 0, stream>>>(deg, rowptr, bsum, N);
    k_scanB<<<1, 128, 0, stream>>>(bsum, boff, nscan);
    k_scanC<<<nscan, 256, 0, stream>>>(rowptr, boff, N);
    k_fill<<<eb, 256, 0, stream>>>(src, dst, perm, dinv, rowptr, cursor,
                                   csr, qcsr, ratio, E);

    long n4 = (long)N * IN / 4;
    k_split<<<(int)((n4 + 255) / 256), 256, 0, stream>>>(x, Xhi, n4);
    k_wT<<<(IN * HID + 255) / 256, 256, 0, stream>>>(W1, W1t, IN, HID);
    k_wT<<<(HID * OUT + 255) / 256, 256, 0, stream>>>(W2, W2t, HID, OUT);

    int mblk = (N + 127) / 128;
    int aggb = (N + 3) / 4;

    // layer 1: GEMM -> T table (scaled, coalesced); agg -> Bp, Bn
    k_gemm_mfma<1><<<dim3(HID / 128, mblk), 256, 0, stream>>>(
        Xhi, W1t, Tt, dinv, N, IN, HID, HID, N);
    k_aggT<<<aggb, 256, 0, stream>>>(Tt, rowptr, csr, qcsr, ratio, perm, dinv, b1,
                                     Bp, Bn, N);

    // layer 2: one GEMM over M=2N rows (Bp|Bn contiguous) -> interleaved G2
    int mblk2 = (2 * N + 127) / 128;
    k_gemm_mfma<2><<<dim3(OUT / 128, mblk2), 256, 0, stream>>>(
        Bp, W2t, G2, dinv, 2 * N, HID, OUT, HID, N);
    k_aggT2<<<aggb, 256, 0, stream>>>(G2, rowptr, csr, dinv, b2, Hpos, Hneg, N);

    // summary + discriminator
    k_colsum<<<256, 256, 0, stream>>>(Hpos, colsum, N);
    k_summary<<<1, 128, 0, stream>>>(colsum, Wb, tvec, N);
    int db = (int)(((size_t)N * 2 * 64 + 255) / 256);
    k_disc<<<db, 256, 0, stream>>>(Hpos, Hneg, tvec, bb, out, N);
}